// Round 1
// baseline (231.668 us; speedup 1.0000x reference)
//
#include <hip/hip_runtime.h>

#define FD    41024   // FEATURES_DIM = 64*(64*10+1)
#define KBASE 641     // 64*10+1

__global__ __launch_bounds__(256) void nnue_fwd(
    const int*   __restrict__ boards,
    const float* __restrict__ W_my,  const float* __restrict__ b_my,
    const float* __restrict__ W_opp, const float* __restrict__ b_opp,
    const float* __restrict__ W1,    const float* __restrict__ b1,
    const float* __restrict__ W2,    const float* __restrict__ b2,
    const float* __restrict__ W3,    const float* __restrict__ b3,
    float* __restrict__ out)
{
    __shared__ int   s_off0[64];   // opp-piece offsets (feed W_my / h[0:256])
    __shared__ int   s_off1[64];   // my-piece offsets  (feed W_opp / h[256:512])
    __shared__ int   s_cnt[2];
    __shared__ int   s_kings[2];   // [0]=my king sq, [1]=opp king sq
    __shared__ float s_h[512];
    __shared__ float s_h1[32];

    const int b = blockIdx.x;
    const int t = threadIdx.x;

    if (t < 2) s_cnt[t] = 0;
    __syncthreads();

    if (t < 64) {
        int d = boards[b * 64 + t];
        if (d == 0)       s_kings[0] = t;
        else if (d == 12) s_kings[1] = t;
        else if (d >= 1 && d <= 5) {          // my piece
            int p = atomicAdd(&s_cnt[1], 1);
            s_off1[p] = (d - 1) * 64 + t;
        } else if (d >= 7) {                  // opp piece (7..11)
            int p = atomicAdd(&s_cnt[0], 1);
            s_off0[p] = (11 - d) * 64 + t;
        }
    }
    __syncthreads();

    const int n0 = s_cnt[0], n1 = s_cnt[1];
    const int base0 = s_kings[1] * KBASE;   // opp king window into W_my
    const int base1 = s_kings[0] * KBASE;   // my king window into W_opp

    // h[0:256] = relu(b_my + sum over opp features of W_my[:, base0+off])
    {
        const float* __restrict__ w = W_my + (size_t)t * FD + base0;
        float acc = b_my[t];
        int i = 0;
        for (; i + 4 <= n0; i += 4) {
            float a0 = w[s_off0[i]];
            float a1 = w[s_off0[i + 1]];
            float a2 = w[s_off0[i + 2]];
            float a3 = w[s_off0[i + 3]];
            acc += a0 + a1 + a2 + a3;
        }
        for (; i < n0; i++) acc += w[s_off0[i]];
        s_h[t] = fmaxf(acc, 0.0f);
    }
    // h[256:512] = relu(b_opp + sum over my features of W_opp[:, base1+off])
    {
        const float* __restrict__ w = W_opp + (size_t)t * FD + base1;
        float acc = b_opp[t];
        int i = 0;
        for (; i + 4 <= n1; i += 4) {
            float a0 = w[s_off1[i]];
            float a1 = w[s_off1[i + 1]];
            float a2 = w[s_off1[i + 2]];
            float a3 = w[s_off1[i + 3]];
            acc += a0 + a1 + a2 + a3;
        }
        for (; i < n1; i++) acc += w[s_off1[i]];
        s_h[256 + t] = fmaxf(acc, 0.0f);
    }
    __syncthreads();

    // layer 1: h1[32] = relu(W1[32,512] @ h + b1), 8 lanes per output
    {
        int o = t >> 3, l = t & 7;
        const float* __restrict__ w = W1 + o * 512;
        float p = 0.0f;
        for (int k = l; k < 512; k += 8) p += s_h[k] * w[k];
        p += __shfl_down(p, 4, 8);
        p += __shfl_down(p, 2, 8);
        p += __shfl_down(p, 1, 8);
        if (l == 0) s_h1[o] = fmaxf(p + b1[o], 0.0f);
    }
    __syncthreads();

    // layers 2+3 on wave 0: h2[32] = relu(W2 @ h1 + b2); out = W3 @ h2 + b3
    if (t < 32) {
        const float* __restrict__ w = W2 + t * 32;
        float acc = b2[t];
        for (int k = 0; k < 32; k++) acc += s_h1[k] * w[k];
        float h2 = fmaxf(acc, 0.0f);
        float p = h2 * W3[t];
        p += __shfl_down(p, 16, 32);
        p += __shfl_down(p,  8, 32);
        p += __shfl_down(p,  4, 32);
        p += __shfl_down(p,  2, 32);
        p += __shfl_down(p,  1, 32);
        if (t == 0) out[b] = p + b3[0];
    }
}

extern "C" void kernel_launch(void* const* d_in, const int* in_sizes, int n_in,
                              void* d_out, int out_size, void* d_ws, size_t ws_size,
                              hipStream_t stream) {
    const int*   boards = (const int*)  d_in[0];
    const float* W_my   = (const float*)d_in[1];
    const float* b_my   = (const float*)d_in[2];
    const float* W_opp  = (const float*)d_in[3];
    const float* b_opp  = (const float*)d_in[4];
    const float* W1     = (const float*)d_in[5];
    const float* b1     = (const float*)d_in[6];
    const float* W2     = (const float*)d_in[7];
    const float* b2     = (const float*)d_in[8];
    const float* W3     = (const float*)d_in[9];
    const float* b3     = (const float*)d_in[10];
    float* out = (float*)d_out;

    const int nb = in_sizes[0] / 64;   // B boards
    nnue_fwd<<<nb, 256, 0, stream>>>(boards, W_my, b_my, W_opp, b_opp,
                                     W1, b1, W2, b2, W3, b3, out);
}

// Round 2
// 147.249 us; speedup vs baseline: 1.5733x; 1.5733x over previous
//
#include <hip/hip_runtime.h>

#define FD    41024   // FEATURES_DIM = 64*(64*10+1)
#define KBASE 641     // 64*10+1
#define WIN   320     // hot window: offsets (piece)*64+sq span 0..319
#define NROW  256

// ---------------------------------------------------------------------------
// Transpose the 64 hot king-windows of W_my/W_opp into Wt[m][k][c][r]
// (r contiguous) so the per-feature gather becomes a coalesced 1 KB read.
// block = 320 threads, grid = 2 matrices * 64 kings * 4 row-quarters.
// ---------------------------------------------------------------------------
__global__ __launch_bounds__(320) void transpose_windows(
    const float* __restrict__ W_my, const float* __restrict__ W_opp,
    float* __restrict__ Wt)
{
    __shared__ float tile[32][WIN + 1];   // +1 pad: phase-2 reads stride 321
    const int blk = blockIdx.x;           // 0..511
    const int rq  = blk & 3;              // row quarter (64 rows)
    const int k   = (blk >> 2) & 63;      // king square
    const int m   = blk >> 8;             // 0 = W_my, 1 = W_opp
    const float* __restrict__ W = m ? W_opp : W_my;
    const int t = threadIdx.x;            // 0..319
    const size_t colbase = (size_t)k * KBASE;
    float* __restrict__ dst = Wt + (((size_t)m * 64 + k) * WIN) * NROW;

    for (int chunk = 0; chunk < 2; chunk++) {
        const int rbase = rq * 64 + chunk * 32;
        // phase 1: read 32 rows x 320 cols, coalesced along cols
        for (int rr = 0; rr < 32; rr++)
            tile[rr][t] = W[(size_t)(rbase + rr) * FD + colbase + t];
        __syncthreads();
        // phase 2: write coalesced along rows (128 B per 32-lane group)
        const int rsub  = t & 31;
        const int cbase = t >> 5;         // 0..9
        for (int it = 0; it < 32; it++) {
            const int c = cbase + it * 10;
            dst[(size_t)c * NROW + rbase + rsub] = tile[rsub][c];
        }
        __syncthreads();
    }
}

// ---------------------------------------------------------------------------
// Gather from transposed layout + tiny MLP. One block per board.
// 4 waves split the feature list; each lane owns 4 rows via float4.
// ---------------------------------------------------------------------------
__global__ __launch_bounds__(256) void nnue_fwd_t(
    const int*   __restrict__ boards, const float* __restrict__ Wt,
    const float* __restrict__ b_my,  const float* __restrict__ b_opp,
    const float* __restrict__ W1,    const float* __restrict__ b1,
    const float* __restrict__ W2,    const float* __restrict__ b2,
    const float* __restrict__ W3,    const float* __restrict__ b3,
    float* __restrict__ out)
{
    __shared__ int   s_off0[64];   // opp-piece offsets (feed h[0:256] via W_my)
    __shared__ int   s_off1[64];   // my-piece offsets  (feed h[256:512] via W_opp)
    __shared__ int   s_cnt[2];
    __shared__ int   s_kings[2];   // [0]=my king, [1]=opp king
    __shared__ float s_red0[4][256];
    __shared__ float s_red1[4][256];
    __shared__ float s_h[512];
    __shared__ float s_h1[32];

    const int b = blockIdx.x;
    const int t = threadIdx.x;

    if (t < 2) s_cnt[t] = 0;
    __syncthreads();

    if (t < 64) {
        int d = boards[b * 64 + t];
        if (d == 0)       s_kings[0] = t;
        else if (d == 12) s_kings[1] = t;
        else if (d >= 1 && d <= 5) { int p = atomicAdd(&s_cnt[1], 1); s_off1[p] = (d - 1) * 64 + t; }
        else if (d >= 7)           { int p = atomicAdd(&s_cnt[0], 1); s_off0[p] = (11 - d) * 64 + t; }
    }
    __syncthreads();

    const int n0 = s_cnt[0], n1 = s_cnt[1];
    const int g  = t >> 6;             // wave id 0..3 (wave-uniform)
    const int r4 = (t & 63) << 2;      // row base for this lane's float4
    const float* __restrict__ w0 = Wt + (size_t)s_kings[1] * (WIN * NROW);
    const float* __restrict__ w1 = Wt + ((size_t)64 + (size_t)s_kings[0]) * (WIN * NROW);

    float4 a0 = make_float4(0.f, 0.f, 0.f, 0.f);
    float4 a1 = make_float4(0.f, 0.f, 0.f, 0.f);
    for (int i = g; i < n0; i += 4) {
        const float4 v = *(const float4*)(w0 + s_off0[i] * NROW + r4);
        a0.x += v.x; a0.y += v.y; a0.z += v.z; a0.w += v.w;
    }
    for (int i = g; i < n1; i += 4) {
        const float4 v = *(const float4*)(w1 + s_off1[i] * NROW + r4);
        a1.x += v.x; a1.y += v.y; a1.z += v.z; a1.w += v.w;
    }
    ((float4*)s_red0[g])[t & 63] = a0;
    ((float4*)s_red1[g])[t & 63] = a1;
    __syncthreads();

    {
        float h0 = b_my[t]  + ((s_red0[0][t] + s_red0[1][t]) + (s_red0[2][t] + s_red0[3][t]));
        float h1 = b_opp[t] + ((s_red1[0][t] + s_red1[1][t]) + (s_red1[2][t] + s_red1[3][t]));
        s_h[t]       = fmaxf(h0, 0.0f);
        s_h[256 + t] = fmaxf(h1, 0.0f);
    }
    __syncthreads();

    // layer 1: h1[32] = relu(W1[32,512] @ h + b1), 8 lanes per output
    {
        const int o = t >> 3, l = t & 7;
        const float* __restrict__ w = W1 + o * 512;
        float p = 0.0f;
        for (int k = l; k < 512; k += 8) p += s_h[k] * w[k];
        p += __shfl_down(p, 4, 8);
        p += __shfl_down(p, 2, 8);
        p += __shfl_down(p, 1, 8);
        if (l == 0) s_h1[o] = fmaxf(p + b1[o], 0.0f);
    }
    __syncthreads();

    // layers 2+3 on wave 0
    if (t < 32) {
        const float* __restrict__ w = W2 + t * 32;
        float acc = b2[t];
        for (int k = 0; k < 32; k++) acc += s_h1[k] * w[k];
        float h2 = fmaxf(acc, 0.0f);
        float p = h2 * W3[t];
        p += __shfl_down(p, 16, 32);
        p += __shfl_down(p,  8, 32);
        p += __shfl_down(p,  4, 32);
        p += __shfl_down(p,  2, 32);
        p += __shfl_down(p,  1, 32);
        if (t == 0) out[b] = p + b3[0];
    }
}

// ---------------------------------------------------------------------------
// Fallback (R1 kernel): direct strided gather — used only if d_ws is too small.
// ---------------------------------------------------------------------------
__global__ __launch_bounds__(256) void nnue_fwd(
    const int*   __restrict__ boards,
    const float* __restrict__ W_my,  const float* __restrict__ b_my,
    const float* __restrict__ W_opp, const float* __restrict__ b_opp,
    const float* __restrict__ W1,    const float* __restrict__ b1,
    const float* __restrict__ W2,    const float* __restrict__ b2,
    const float* __restrict__ W3,    const float* __restrict__ b3,
    float* __restrict__ out)
{
    __shared__ int   s_off0[64];
    __shared__ int   s_off1[64];
    __shared__ int   s_cnt[2];
    __shared__ int   s_kings[2];
    __shared__ float s_h[512];
    __shared__ float s_h1[32];

    const int b = blockIdx.x;
    const int t = threadIdx.x;

    if (t < 2) s_cnt[t] = 0;
    __syncthreads();

    if (t < 64) {
        int d = boards[b * 64 + t];
        if (d == 0)       s_kings[0] = t;
        else if (d == 12) s_kings[1] = t;
        else if (d >= 1 && d <= 5) { int p = atomicAdd(&s_cnt[1], 1); s_off1[p] = (d - 1) * 64 + t; }
        else if (d >= 7)           { int p = atomicAdd(&s_cnt[0], 1); s_off0[p] = (11 - d) * 64 + t; }
    }
    __syncthreads();

    const int n0 = s_cnt[0], n1 = s_cnt[1];
    const int base0 = s_kings[1] * KBASE;
    const int base1 = s_kings[0] * KBASE;

    {
        const float* __restrict__ w = W_my + (size_t)t * FD + base0;
        float acc = b_my[t];
        for (int i = 0; i < n0; i++) acc += w[s_off0[i]];
        s_h[t] = fmaxf(acc, 0.0f);
    }
    {
        const float* __restrict__ w = W_opp + (size_t)t * FD + base1;
        float acc = b_opp[t];
        for (int i = 0; i < n1; i++) acc += w[s_off1[i]];
        s_h[256 + t] = fmaxf(acc, 0.0f);
    }
    __syncthreads();

    {
        const int o = t >> 3, l = t & 7;
        const float* __restrict__ w = W1 + o * 512;
        float p = 0.0f;
        for (int k = l; k < 512; k += 8) p += s_h[k] * w[k];
        p += __shfl_down(p, 4, 8);
        p += __shfl_down(p, 2, 8);
        p += __shfl_down(p, 1, 8);
        if (l == 0) s_h1[o] = fmaxf(p + b1[o], 0.0f);
    }
    __syncthreads();

    if (t < 32) {
        const float* __restrict__ w = W2 + t * 32;
        float acc = b2[t];
        for (int k = 0; k < 32; k++) acc += s_h1[k] * w[k];
        float h2 = fmaxf(acc, 0.0f);
        float p = h2 * W3[t];
        p += __shfl_down(p, 16, 32);
        p += __shfl_down(p,  8, 32);
        p += __shfl_down(p,  4, 32);
        p += __shfl_down(p,  2, 32);
        p += __shfl_down(p,  1, 32);
        if (t == 0) out[b] = p + b3[0];
    }
}

extern "C" void kernel_launch(void* const* d_in, const int* in_sizes, int n_in,
                              void* d_out, int out_size, void* d_ws, size_t ws_size,
                              hipStream_t stream) {
    const int*   boards = (const int*)  d_in[0];
    const float* W_my   = (const float*)d_in[1];
    const float* b_my   = (const float*)d_in[2];
    const float* W_opp  = (const float*)d_in[3];
    const float* b_opp  = (const float*)d_in[4];
    const float* W1     = (const float*)d_in[5];
    const float* b1     = (const float*)d_in[6];
    const float* W2     = (const float*)d_in[7];
    const float* b2     = (const float*)d_in[8];
    const float* W3     = (const float*)d_in[9];
    const float* b3     = (const float*)d_in[10];
    float* out = (float*)d_out;

    const int nb = in_sizes[0] / 64;
    const size_t wt_bytes = (size_t)2 * 64 * WIN * NROW * sizeof(float);  // ~42 MB

    if (ws_size >= wt_bytes) {
        float* Wt = (float*)d_ws;
        transpose_windows<<<512, 320, 0, stream>>>(W_my, W_opp, Wt);
        nnue_fwd_t<<<nb, 256, 0, stream>>>(boards, Wt, b_my, b_opp,
                                           W1, b1, W2, b2, W3, b3, out);
    } else {
        nnue_fwd<<<nb, 256, 0, stream>>>(boards, W_my, b_my, W_opp, b_opp,
                                         W1, b1, W2, b2, W3, b3, out);
    }
}